// Round 8
// baseline (456.275 us; speedup 1.0000x reference)
//
#include <hip/hip_runtime.h>
#include <hip/hip_bf16.h>
#include <cstdint>

#define DMODEL 1024
#define DHALF  512
#define DINNER 1024
#define DSTATE 16
#define DTRANK 32
#define LSEQ   4096
#define BBATCH 2
#define MROWS  (BBATCH*LSEQ)   // 8192
#define SCH    128             // scan chunks
#define SCT    32              // steps per chunk (SCH*SCT == LSEQ)

using bf16 = __bf16;
using bf16x8 = __attribute__((ext_vector_type(8))) __bf16;
using f32x4  = __attribute__((ext_vector_type(4))) float;
using f32x2  = __attribute__((ext_vector_type(2))) float;

__device__ __forceinline__ float sigmoidf_(float x) { return 1.f / (1.f + __expf(-x)); }
__device__ __forceinline__ float softplusf_(float x) { return fmaxf(x, 0.f) + log1pf(__expf(-fabsf(x))); }

// async global->LDS, 16B per lane; LDS dest = wave-uniform base + lane*16
__device__ __forceinline__ void glds16(const bf16* g, bf16* l) {
    __builtin_amdgcn_global_load_lds(
        (const __attribute__((address_space(1))) void*)g,
        (__attribute__((address_space(3))) void*)l, 16, 0, 0);
}

// ---------------------------------------------------------------- LayerNorm
__global__ __launch_bounds__(256) void ln_kernel(
    const float* __restrict__ x, const float* __restrict__ w,
    const float* __restrict__ b, bf16* __restrict__ xn)
{
    const int row = blockIdx.x;
    const int tid = threadIdx.x;
    const float4 v = *(const float4*)&x[(size_t)row * DMODEL + tid * 4];
    float s  = v.x + v.y + v.z + v.w;
    float s2 = v.x * v.x + v.y * v.y + v.z * v.z + v.w * v.w;
#pragma unroll
    for (int off = 1; off < 64; off <<= 1) {
        s  += __shfl_xor(s, off);
        s2 += __shfl_xor(s2, off);
    }
    __shared__ float red[8];
    const int wid = tid >> 6;
    if ((tid & 63) == 0) { red[wid] = s; red[4 + wid] = s2; }
    __syncthreads();
    s  = red[0] + red[1] + red[2] + red[3];
    s2 = red[4] + red[5] + red[6] + red[7];
    const float mu   = s * (1.f / DMODEL);
    const float var  = s2 * (1.f / DMODEL) - mu * mu;
    const float rstd = rsqrtf(var + 1e-5f);
    const float4 wv = *(const float4*)&w[tid * 4];
    const float4 bv = *(const float4*)&b[tid * 4];
    union { bf16 o[4]; uint2 u; } pk;
    pk.o[0] = (bf16)((v.x - mu) * rstd * wv.x + bv.x);
    pk.o[1] = (bf16)((v.y - mu) * rstd * wv.y + bv.y);
    pk.o[2] = (bf16)((v.z - mu) * rstd * wv.z + bv.z);
    pk.o[3] = (bf16)((v.w - mu) * rstd * wv.w + bv.w);
    *(uint2*)&xn[(size_t)row * DMODEL + tid * 4] = pk.u;
}

// ------------------------------------------------------- weight fp32->bf16
__global__ __launch_bounds__(256) void cvt_weights_kernel(
    const float* __restrict__ s0, const float* __restrict__ s1,
    const float* __restrict__ s2, const float* __restrict__ s3,
    const float* __restrict__ s4, const float* __restrict__ s5,
    const float* __restrict__ s6, const float* __restrict__ s7,
    bf16* __restrict__ d0, bf16* __restrict__ d1, bf16* __restrict__ d2,
    bf16* __restrict__ d3, bf16* __restrict__ d4, bf16* __restrict__ d5,
    bf16* __restrict__ d6, bf16* __restrict__ d7)
{
    const size_t gid = ((size_t)blockIdx.x * 256 + threadIdx.x) * 4;
    const float* s; bf16* dst; size_t off;
    if      (gid < 1048576) { s = s0; dst = d0; off = gid; }
    else if (gid < 2097152) { s = s1; dst = d1; off = gid - 1048576; }
    else if (gid < 2162688) { s = s2; dst = d2; off = gid - 2097152; }
    else if (gid < 2228224) { s = s3; dst = d3; off = gid - 2162688; }
    else if (gid < 2752512) { s = s4; dst = d4; off = gid - 2228224; }
    else if (gid < 3276800) { s = s5; dst = d5; off = gid - 2752512; }
    else if (gid < 3309568) { s = s6; dst = d6; off = gid - 3276800; }
    else if (gid < 3342336) { s = s7; dst = d7; off = gid - 3309568; }
    else return;
    const float4 v = *(const float4*)&s[off];
    union { bf16 o[4]; uint2 u; } pk;
    pk.o[0] = (bf16)v.x; pk.o[1] = (bf16)v.y; pk.o[2] = (bf16)v.z; pk.o[3] = (bf16)v.w;
    *(uint2*)&dst[off] = pk.u;
}

// ----------------------------------------------------------------- GEMM
// C[m,n] = sum_k A[m,k] * W[n,k]. m97 structure: global_load_lds(16B) into
// LINEAR LDS [rows][32], 2 barriers per K-step. Optional split-K (KS>1):
// blockIdx.z = dir*KS + ks, each split covers K/KS.
// EPI 0: bf16 store   1: f32+bf16 dual   2: softplus(v+bias[col]) -> bf16
// EPI 3: v + residual f32   4: f32 partial store (indexed by bz slice)
template<int BM, int BN, int WTM, int WTN, int EPI, int KS = 1>
__global__ __launch_bounds__(256) void gemm_k(
    const bf16* __restrict__ A0, long aDirStride, int lda,
    const bf16* __restrict__ W0, const bf16* __restrict__ W1, int ldw,
    void* __restrict__ C0, long cDirStride, int ldc,
    void* __restrict__ C1, long c1DirStride,
    const float* __restrict__ X0, const float* __restrict__ X1,
    int K)
{
    constexpr int WGN = BN / (WTN * 16);
    static_assert((BM * 32) % 2048 == 0 && (BN * 32) % 2048 == 0, "tile");
    __shared__ alignas(16) bf16 As[BM * 32];
    __shared__ alignas(16) bf16 Bs[BN * 32];
    const int tid = threadIdx.x;
    const int wid = tid >> 6, lane = tid & 63;
    const int wr = wid / WGN, wc = wid % WGN;
    const int bx = blockIdx.x, by = blockIdx.y, bz = blockIdx.z;
    const int dirz = bz / KS, ks = bz % KS;
    const bf16* A = A0 + (long)dirz * aDirStride + (long)by * BM * lda;
    const bf16* W = (dirz ? W1 : W0) + (long)bx * BN * ldw;
    f32x4 acc[WTM][WTN] = {};
    const int kBeg = ks * (K / KS), kEnd = (ks + 1) * (K / KS);
    for (int k0 = kBeg; k0 < kEnd; k0 += 32) {
        constexpr int AP = BM * 32 / 2048;
#pragma unroll
        for (int p = 0; p < AP; ++p) {
            const int idx = (p * 256 + tid) * 8;
            const int r = idx >> 5, c = idx & 31;
            glds16(&A[(long)r * lda + k0 + c], &As[p * 2048 + wid * 512]);
        }
        constexpr int BP = BN * 32 / 2048;
#pragma unroll
        for (int p = 0; p < BP; ++p) {
            const int idx = (p * 256 + tid) * 8;
            const int r = idx >> 5, c = idx & 31;
            glds16(&W[(long)r * ldw + k0 + c], &Bs[p * 2048 + wid * 512]);
        }
        __syncthreads();
        const int rA = lane & 15, kO = (lane >> 4) * 8;
        bf16x8 af[WTM], bw[WTN];
#pragma unroll
        for (int i = 0; i < WTM; ++i)
            af[i] = *(const bf16x8*)&As[(wr * WTM * 16 + i * 16 + rA) * 32 + kO];
#pragma unroll
        for (int j = 0; j < WTN; ++j)
            bw[j] = *(const bf16x8*)&Bs[(wc * WTN * 16 + j * 16 + rA) * 32 + kO];
#pragma unroll
        for (int i = 0; i < WTM; ++i)
#pragma unroll
            for (int j = 0; j < WTN; ++j)
                acc[i][j] = __builtin_amdgcn_mfma_f32_16x16x32_bf16(af[i], bw[j], acc[i][j], 0, 0, 0);
        __syncthreads();
    }
    const int rl = (lane >> 4) * 4, cl = lane & 15;
    const int rowBase = by * BM + wr * WTM * 16;
    const int colBase = bx * BN + wc * WTN * 16;
#pragma unroll
    for (int i = 0; i < WTM; ++i)
#pragma unroll
        for (int j = 0; j < WTN; ++j) {
#pragma unroll
            for (int r = 0; r < 4; ++r) {
                const int row = rowBase + i * 16 + rl + r;
                const int col = colBase + j * 16 + cl;
                const float v = acc[i][j][r];
                if constexpr (EPI == 0) {
                    ((bf16*)C0 + (long)dirz * cDirStride)[(long)row * ldc + col] = (bf16)v;
                } else if constexpr (EPI == 1) {
                    ((float*)C0 + (long)dirz * cDirStride)[(long)row * ldc + col] = v;
                    ((bf16*)C1 + (long)dirz * c1DirStride)[(long)row * ldc + col] = (bf16)v;
                } else if constexpr (EPI == 2) {
                    const float* bias = dirz ? X1 : X0;
                    ((bf16*)C0 + (long)dirz * cDirStride)[(long)row * ldc + col] =
                        (bf16)softplusf_(v + bias[col]);
                } else if constexpr (EPI == 3) {
                    const long idx = (long)row * ldc + col;
                    ((float*)C0 + (long)dirz * cDirStride)[idx] = v + (X0 + (long)dirz * cDirStride)[idx];
                } else {
                    ((float*)C0 + (long)bz * cDirStride)[(long)row * ldc + col] = v;
                }
            }
        }
}

// ------------------------------------------- x_proj split-K partial reduce
__global__ __launch_bounds__(256) void xproj_reduce(
    const float* __restrict__ part, float* __restrict__ xdbl, bf16* __restrict__ xdbl_bf)
{
    const size_t gid = (size_t)blockIdx.x * 256 + threadIdx.x;   // 262144
    const size_t e4 = gid * 4;
    const int dir = (int)(e4 / ((size_t)MROWS * 64));
    const size_t e = e4 - (size_t)dir * MROWS * 64;
    const float* p = part + (size_t)dir * 4 * MROWS * 64 + e;
    float4 s0 = *(const float4*)&p[0];
    const float4 s1 = *(const float4*)&p[(size_t)MROWS * 64];
    const float4 s2 = *(const float4*)&p[(size_t)2 * MROWS * 64];
    const float4 s3 = *(const float4*)&p[(size_t)3 * MROWS * 64];
    s0.x += s1.x + s2.x + s3.x;
    s0.y += s1.y + s2.y + s3.y;
    s0.z += s1.z + s2.z + s3.z;
    s0.w += s1.w + s2.w + s3.w;
    *(float4*)&xdbl[e4] = s0;
    union { bf16 o[4]; uint2 u; } pk;
    pk.o[0] = (bf16)s0.x; pk.o[1] = (bf16)s0.y; pk.o[2] = (bf16)s0.z; pk.o[3] = (bf16)s0.w;
    *(uint2*)&xdbl_bf[e4] = pk.u;
}

// --------------------------------------------------- depthwise conv4 + SiLU
#define CT 8
__global__ __launch_bounds__(256) void conv_silu_kernel(
    const bf16* __restrict__ xz, bf16* __restrict__ xc,
    const float* __restrict__ cwF, const float* __restrict__ cbF,
    const float* __restrict__ cwB, const float* __restrict__ cbB)
{
    const size_t gid = (size_t)blockIdx.x * 256 + threadIdx.x; // 2^18
    const int g = (int)(gid & 127);            // channel group (8 ch)
    const int tt = (int)((gid >> 7) & (LSEQ / CT - 1));
    const int b = (int)((gid >> 16) & 1);
    const int dir = (int)(gid >> 17);          // wave-uniform
    const int d0 = g * 8;
    const float* cw = dir ? cwB : cwF;
    const float* cb = dir ? cbB : cbF;
    float bias[8];
#pragma unroll
    for (int e = 0; e < 8; e += 4) *(float4*)&bias[e] = *(const float4*)&cb[d0 + e];
    float4 wv[8];
#pragma unroll
    for (int e = 0; e < 8; ++e) wv[e] = *(const float4*)&cw[(d0 + e) * 4];
    const int t0 = tt * CT;
    const size_t rowBase = (size_t)dir * MROWS * 2048 + (size_t)b * LSEQ * 2048;
    const bf16* src = xz + rowBase + d0;
    bf16* dst = xc + (size_t)dir * MROWS * DINNER + (size_t)b * LSEQ * DINNER
                + (size_t)t0 * DINNER + d0;

    float w0[8] = {}, w1[8] = {}, w2[8] = {};
    auto loadRow = [&](int ts, float* r) {
        if (ts >= 0 && ts < LSEQ) {
            const bf16x8 v = *(const bf16x8*)&src[(size_t)ts * 2048];
#pragma unroll
            for (int e = 0; e < 8; ++e) r[e] = (float)v[e];
        } else {
#pragma unroll
            for (int e = 0; e < 8; ++e) r[e] = 0.f;
        }
    };
    if (!dir) { loadRow(t0 - 3, w0); loadRow(t0 - 2, w1); loadRow(t0 - 1, w2); }
    else      { loadRow(t0,     w0); loadRow(t0 + 1, w1); loadRow(t0 + 2, w2); }

#pragma unroll
    for (int i = 0; i < CT; ++i) {
        float w3[8];
        loadRow(dir ? (t0 + i + 3) : (t0 + i), w3);
        bf16x8 o;
        if (!dir) {
#pragma unroll
            for (int e = 0; e < 8; ++e) {
                float acc = bias[e];
                acc = fmaf(wv[e].x, w0[e], acc);
                acc = fmaf(wv[e].y, w1[e], acc);
                acc = fmaf(wv[e].z, w2[e], acc);
                acc = fmaf(wv[e].w, w3[e], acc);
                const float s = acc * sigmoidf_(acc);
                o[e] = (bf16)s;
            }
        } else {
#pragma unroll
            for (int e = 0; e < 8; ++e) {
                float acc = bias[e];
                acc = fmaf(wv[e].w, w0[e], acc);
                acc = fmaf(wv[e].z, w1[e], acc);
                acc = fmaf(wv[e].y, w2[e], acc);
                acc = fmaf(wv[e].x, w3[e], acc);
                const float s = acc * sigmoidf_(acc);
                o[e] = (bf16)s;
            }
        }
        *(bf16x8*)&dst[(size_t)i * DINNER] = o;
#pragma unroll
        for (int e = 0; e < 8; ++e) { w0[e] = w1[e]; w1[e] = w2[e]; w2[e] = w3[e]; }
    }
}

// ------------------------------------------------- chunked selective scan
// lane = one channel d; 16 states in registers as 4 x f32x4.
// B(/C) rows for the chunk staged in LDS once; per-step reads are uniform
// ds_read_b128 broadcasts (no SGPR pressure, pipelineable).
// Fast path exploits a[n] == -(n+1): dA[n] = q^(n+1), q = exp(-dt).
__global__ __launch_bounds__(256) void scan_part1(
    const bf16* __restrict__ dt, const bf16* __restrict__ xc,
    const float* __restrict__ xdbl,
    float* __restrict__ hend, float* __restrict__ sdtOut,
    const float* __restrict__ AlogF, const float* __restrict__ AlogB)
{
    __shared__ alignas(16) float bs[SCT][16];
    const int d = blockIdx.x * 256 + threadIdx.x;
    const int chunk = blockIdx.y;
    const int sb = blockIdx.z;
    const int dir = sb >> 1, b = sb & 1;
    const float* Alog = dir ? AlogB : AlogF;
    float a[16];
#pragma unroll
    for (int n = 0; n < 16; n += 4)
        *(float4*)&a[n] = *(const float4*)&Alog[d * 16 + n];
#pragma unroll
    for (int n = 0; n < 16; ++n) a[n] = -__expf(a[n]);
    bool fast = true;
#pragma unroll
    for (int n = 0; n < 16; ++n) fast = fast && (fabsf(a[n] + (float)(n + 1)) <= 1e-3f * (n + 1));
    const size_t base1 = (size_t)dir * MROWS * DINNER + (size_t)b * LSEQ * DINNER;
    const size_t base64 = (size_t)dir * MROWS * 64 + (size_t)b * LSEQ * 64;
    const int t0 = dir ? (LSEQ - 1) : 0;
    const int stp = dir ? -1 : 1;
    const int ts = t0 + stp * (chunk * SCT);
    // stage B rows (cols 32..47 of xdbl) for all SCT steps: 512 floats
    {
        const int s = threadIdx.x >> 3;
        const int c = (threadIdx.x & 7) * 2;
        const float* srcRow = xdbl + base64 + (size_t)(ts + stp * s) * 64 + 32;
        *(float2*)&bs[s][c] = *(const float2*)&srcRow[c];
    }
    __syncthreads();
    const bf16* pdt = dt + base1 + (size_t)ts * DINNER + d;
    const bf16* pxc = xc + base1 + (size_t)ts * DINNER + d;
    const long s1 = (long)stp * DINNER;
    float sacc = 0.f;
    f32x4 h4[4] = {};
    if (fast) {
#pragma unroll 4
        for (int i = 0; i < SCT; ++i) {
            const float dtv = (float)*pdt;
            const float u = (float)*pxc;
            const float dtu = dtv * u;
            sacc += dtv;
            const f32x4* rowB = (const f32x4*)&bs[i][0];
            const float q = __expf(-dtv);
            const float q2 = q * q, q3 = q2 * q, q4 = q2 * q2;
            f32x4 p = {q, q2, q3, q4};
            const f32x4 q4v = {q4, q4, q4, q4};
#pragma unroll
            for (int j = 0; j < 4; ++j) {
                const f32x4 B4 = rowB[j];
                h4[j] = __builtin_elementwise_fma(h4[j], p, B4 * dtu);
                p = p * q4v;
            }
            pdt += s1; pxc += s1;
        }
    } else {
#pragma unroll 4
        for (int i = 0; i < SCT; ++i) {
            const float dtv = (float)*pdt;
            const float u = (float)*pxc;
            const float dtu = dtv * u;
            sacc += dtv;
            const f32x4* rowB = (const f32x4*)&bs[i][0];
#pragma unroll
            for (int j = 0; j < 4; ++j) {
                const f32x4 B4 = rowB[j];
                const f32x4 dA = {__expf(dtv * a[4 * j]), __expf(dtv * a[4 * j + 1]),
                                  __expf(dtv * a[4 * j + 2]), __expf(dtv * a[4 * j + 3])};
                h4[j] = __builtin_elementwise_fma(h4[j], dA, B4 * dtu);
            }
            pdt += s1; pxc += s1;
        }
    }
    const size_t o = ((size_t)sb * SCH + chunk) * 16384 + (size_t)d * 16;
#pragma unroll
    for (int j = 0; j < 4; ++j) *(f32x4*)&hend[o + 4 * j] = h4[j];
    sdtOut[((size_t)sb * SCH + chunk) * 1024 + d] = sacc;
}

// combine chunk summaries across chunks; hend[c] becomes h_in for chunk c.
__global__ __launch_bounds__(256) void scan_part2(
    float* __restrict__ hend, const float* __restrict__ sdt,
    const float* __restrict__ AlogF, const float* __restrict__ AlogB)
{
    const size_t gid = (size_t)blockIdx.x * 256 + threadIdx.x;  // 65536
    const int sb = (int)(gid >> 14);
    const int dn = (int)(gid & 16383);
    const int d = dn >> 4;
    const float* Alog = (sb >> 1) ? AlogB : AlogF;
    const float a_n = -__expf(Alog[dn]);
    float h = 0.f;
    size_t idx = (size_t)sb * SCH * 16384 + dn;
    size_t sidx = (size_t)sb * SCH * 1024 + d;
#pragma unroll 4
    for (int c = 0; c < SCH; ++c) {
        const float sd = sdt[sidx];
        const float pe = __expf(a_n * sd);
        const float he = hend[idx];
        hend[idx] = h;
        h = fmaf(pe, h, he);
        idx += 16384; sidx += 1024;
    }
}

// final pass: chunk scan from h_in; y = sum_n h*C; gate with silu(z)
__global__ __launch_bounds__(256) void scan_part3(
    const bf16* __restrict__ dt, const bf16* __restrict__ xc,
    const float* __restrict__ xdbl, const bf16* __restrict__ xz,
    const float* __restrict__ hin, bf16* __restrict__ yg,
    const float* __restrict__ AlogF, const float* __restrict__ AlogB,
    const float* __restrict__ DF, const float* __restrict__ DB)
{
    __shared__ alignas(16) float bc[SCT][32];
    const int d = blockIdx.x * 256 + threadIdx.x;
    const int chunk = blockIdx.y;
    const int sb = blockIdx.z;
    const int dir = sb >> 1, b = sb & 1;
    const float* Alog = dir ? AlogB : AlogF;
    const float* Dw = dir ? DB : DF;
    float a[16];
#pragma unroll
    for (int n = 0; n < 16; n += 4)
        *(float4*)&a[n] = *(const float4*)&Alog[d * 16 + n];
#pragma unroll
    for (int n = 0; n < 16; ++n) a[n] = -__expf(a[n]);
    bool fast = true;
#pragma unroll
    for (int n = 0; n < 16; ++n) fast = fast && (fabsf(a[n] + (float)(n + 1)) <= 1e-3f * (n + 1));
    const float Dv = Dw[d];
    const size_t base1 = (size_t)dir * MROWS * DINNER + (size_t)b * LSEQ * DINNER;
    const size_t base64 = (size_t)dir * MROWS * 64 + (size_t)b * LSEQ * 64;
    const size_t baseZ = (size_t)dir * MROWS * 2048 + (size_t)b * LSEQ * 2048;
    const int t0 = dir ? (LSEQ - 1) : 0;
    const int stp = dir ? -1 : 1;
    const int ts = t0 + stp * (chunk * SCT);
    // stage B+C rows (cols 32..63 of xdbl) for all SCT steps: 1024 floats
    {
        const int s = threadIdx.x >> 3;
        const int c = (threadIdx.x & 7) * 4;
        const float* srcRow = xdbl + base64 + (size_t)(ts + stp * s) * 64 + 32;
        *(float4*)&bc[s][c] = *(const float4*)&srcRow[c];
    }
    __syncthreads();
    const bf16* pdt = dt + base1 + (size_t)ts * DINNER + d;
    const bf16* pxc = xc + base1 + (size_t)ts * DINNER + d;
    const bf16* pz = xz + baseZ + (size_t)ts * 2048 + 1024 + d;
    bf16* pyg = yg + base1 + (size_t)ts * DINNER + d;
    const long s1 = (long)stp * DINNER, sZ = (long)stp * 2048;
    f32x4 h4[4];
    const size_t o = ((size_t)sb * SCH + chunk) * 16384 + (size_t)d * 16;
#pragma unroll
    for (int j = 0; j < 4; ++j) h4[j] = *(const f32x4*)&hin[o + 4 * j];
    if (fast) {
#pragma unroll 4
        for (int i = 0; i < SCT; ++i) {
            const float dtv = (float)*pdt;
            const float u = (float)*pxc;
            const float dtu = dtv * u;
            const f32x4* rowB = (const f32x4*)&bc[i][0];
            const f32x4* rowC = (const f32x4*)&bc[i][16];
            const float q = __expf(-dtv);
            const float q2 = q * q, q3 = q2 * q, q4 = q2 * q2;
            f32x4 p = {q, q2, q3, q4};
            const f32x4 q4v = {q4, q4, q4, q4};
            f32x4 y4 = {0.f, 0.f, 0.f, 0.f};
#pragma unroll
            for (int j = 0; j < 4; ++j) {
                const f32x4 B4 = rowB[j];
                const f32x4 C4 = rowC[j];
                h4[j] = __builtin_elementwise_fma(h4[j], p, B4 * dtu);
                y4 = __builtin_elementwise_fma(h4[j], C4, y4);
                p = p * q4v;
            }
            const float y = (y4[0] + y4[1]) + (y4[2] + y4[3]);
            const float z = (float)*pz;
            const float out = (y + Dv * u) * (z * sigmoidf_(z));
            *pyg = (bf16)out;
            pdt += s1; pxc += s1; pz += sZ; pyg += s1;
        }
    } else {
#pragma unroll 4
        for (int i = 0; i < SCT; ++i) {
            const float dtv = (float)*pdt;
            const float u = (float)*pxc;
            const float dtu = dtv * u;
            const f32x4* rowB = (const f32x4*)&bc[i][0];
            const f32x4* rowC = (const f32x4*)&bc[i][16];
            f32x4 y4 = {0.f, 0.f, 0.f, 0.f};
#pragma unroll
            for (int j = 0; j < 4; ++j) {
                const f32x4 B4 = rowB[j];
                const f32x4 C4 = rowC[j];
                const f32x4 dA = {__expf(dtv * a[4 * j]), __expf(dtv * a[4 * j + 1]),
                                  __expf(dtv * a[4 * j + 2]), __expf(dtv * a[4 * j + 3])};
                h4[j] = __builtin_elementwise_fma(h4[j], dA, B4 * dtu);
                y4 = __builtin_elementwise_fma(h4[j], C4, y4);
            }
            const float y = (y4[0] + y4[1]) + (y4[2] + y4[3]);
            const float z = (float)*pz;
            const float out = (y + Dv * u) * (z * sigmoidf_(z));
            *pyg = (bf16)out;
            pdt += s1; pxc += s1; pz += sZ; pyg += s1;
        }
    }
}

// ------------------------------------------------------------------- launch
extern "C" void kernel_launch(void* const* d_in, const int* in_sizes, int n_in,
                              void* d_out, int out_size, void* d_ws, size_t ws_size,
                              hipStream_t stream)
{
    const float* x      = (const float*)d_in[0];
    const float* norm_w = (const float*)d_in[1];
    const float* norm_b = (const float*)d_in[2];
    const float* ipF  = (const float*)d_in[3];
    const float* cwF  = (const float*)d_in[4];
    const float* cbF  = (const float*)d_in[5];
    const float* xpF  = (const float*)d_in[6];
    const float* dtwF = (const float*)d_in[7];
    const float* dtbF = (const float*)d_in[8];
    const float* AlF  = (const float*)d_in[9];
    const float* DF   = (const float*)d_in[10];
    const float* opF  = (const float*)d_in[11];
    const float* ipB  = (const float*)d_in[12];
    const float* cwB  = (const float*)d_in[13];
    const float* cbB  = (const float*)d_in[14];
    const float* xpB  = (const float*)d_in[15];
    const float* dtwB = (const float*)d_in[16];
    const float* dtbB = (const float*)d_in[17];
    const float* AlB  = (const float*)d_in[18];
    const float* DB   = (const float*)d_in[19];
    const float* opB  = (const float*)d_in[20];

    char* ws = (char*)d_ws;
    size_t off = 0;
    auto alloc = [&](size_t bytes) -> void* {
        void* p = ws + off;
        off += (bytes + 255) & ~(size_t)255;
        return p;
    };
    bf16*  xn      = (bf16*)alloc((size_t)MROWS * DMODEL * 2);
    bf16*  win     = (bf16*)alloc((size_t)2 * 2048 * 512 * 2);
    bf16*  wxp     = (bf16*)alloc((size_t)2 * 64 * 1024 * 2);
    bf16*  wop     = (bf16*)alloc((size_t)2 * 512 * 1024 * 2);
    bf16*  wdt     = (bf16*)alloc((size_t)2 * 1024 * 32 * 2);
    bf16*  xz      = (bf16*)alloc((size_t)2 * MROWS * 2048 * 2);
    bf16*  xc      = (bf16*)alloc((size_t)2 * MROWS * 1024 * 2);
    float* xdbl    = (float*)alloc((size_t)2 * MROWS * 64 * 4);
    bf16*  xdbl_bf = (bf16*)alloc((size_t)2 * MROWS * 64 * 2);
    bf16*  dt      = (bf16*)alloc((size_t)2 * MROWS * 1024 * 2);
    bf16*  yg      = (bf16*)alloc((size_t)2 * MROWS * 1024 * 2);
    float* hend    = (float*)alloc((size_t)4 * SCH * 16384 * 4);
    float* sdt     = (float*)alloc((size_t)4 * SCH * 1024 * 4);
    float* xpart   = (float*)alloc((size_t)8 * MROWS * 64 * 4);

    cvt_weights_kernel<<<3264, 256, 0, stream>>>(
        ipF, ipB, xpF, xpB, opF, opB, dtwF, dtwB,
        win, win + 2048 * 512, wxp, wxp + 64 * 1024,
        wop, wop + 512 * 1024, wdt, wdt + 1024 * 32);

    ln_kernel<<<MROWS, 256, 0, stream>>>(x, norm_w, norm_b, xn);

    // in_proj: [8192,512] x [2048,512]^T -> xz bf16 [dir][8192][2048]
    gemm_k<128, 128, 4, 4, 0><<<dim3(16, 64, 2), 256, 0, stream>>>(
        xn, 512, DMODEL, win, win + 2048 * 512, 512,
        xz, (long)MROWS * 2048, 2048, nullptr, 0, nullptr, nullptr, 512);

    conv_silu_kernel<<<1024, 256, 0, stream>>>(xz, xc, cwF, cbF, cwB, cbB);

    // x_proj: split-K=4 partials -> reduce to f32 + bf16 shadow
    gemm_k<64, 64, 2, 2, 4, 4><<<dim3(1, 128, 8), 256, 0, stream>>>(
        xc, (long)MROWS * 1024, 1024, wxp, wxp + 64 * 1024, 1024,
        xpart, (long)MROWS * 64, 64, nullptr, 0, nullptr, nullptr, 1024);
    xproj_reduce<<<1024, 256, 0, stream>>>(xpart, xdbl, xdbl_bf);

    // dt_proj: [8192,32] x [1024,32]^T -> softplus(+bias) bf16
    gemm_k<128, 128, 4, 4, 2><<<dim3(8, 64, 2), 256, 0, stream>>>(
        xdbl_bf, (long)MROWS * 64, 64, wdt, wdt + 1024 * 32, 32,
        dt, (long)MROWS * 1024, 1024, nullptr, 0, dtbF, dtbB, 32);

    // chunked scan: 128 chunks x 32 steps, lane = channel, B/C via LDS
    scan_part1<<<dim3(4, SCH, 4), 256, 0, stream>>>(dt, xc, xdbl, hend, sdt, AlF, AlB);
    scan_part2<<<256, 256, 0, stream>>>(hend, sdt, AlF, AlB);
    scan_part3<<<dim3(4, SCH, 4), 256, 0, stream>>>(dt, xc, xdbl, xz, hend, yg,
                                                    AlF, AlB, DF, DB);

    // out_proj + residual: [8192,1024] x [512,1024]^T -> d_out[row][dir*512+col]
    gemm_k<128, 128, 4, 4, 3><<<dim3(4, 64, 2), 256, 0, stream>>>(
        yg, (long)MROWS * 1024, 1024, wop, wop + 512 * 1024, 1024,
        d_out, 512, 1024, nullptr, 0, x, nullptr, 1024);
}

// Round 10
// 390.295 us; speedup vs baseline: 1.1691x; 1.1691x over previous
//
#include <hip/hip_runtime.h>
#include <hip/hip_bf16.h>
#include <cstdint>

#define DMODEL 1024
#define DHALF  512
#define DINNER 1024
#define DSTATE 16
#define DTRANK 32
#define LSEQ   4096
#define BBATCH 2
#define MROWS  (BBATCH*LSEQ)   // 8192
#define SCH    128             // scan chunks
#define SCT    32              // steps per chunk (SCH*SCT == LSEQ)

using bf16 = __bf16;
using bf16x8 = __attribute__((ext_vector_type(8))) __bf16;
using f32x4  = __attribute__((ext_vector_type(4))) float;
using f32x2  = __attribute__((ext_vector_type(2))) float;

__device__ __forceinline__ float sigmoidf_(float x) { return 1.f / (1.f + __expf(-x)); }
__device__ __forceinline__ float softplusf_(float x) { return fmaxf(x, 0.f) + log1pf(__expf(-fabsf(x))); }

// async global->LDS, 16B per lane; LDS dest = wave-uniform base + lane*16
__device__ __forceinline__ void glds16(const bf16* g, bf16* l) {
    __builtin_amdgcn_global_load_lds(
        (const __attribute__((address_space(1))) void*)g,
        (__attribute__((address_space(3))) void*)l, 16, 0, 0);
}

// ---------------------------------------------------------------- LayerNorm
__global__ __launch_bounds__(256) void ln_kernel(
    const float* __restrict__ x, const float* __restrict__ w,
    const float* __restrict__ b, bf16* __restrict__ xn)
{
    const int row = blockIdx.x;
    const int tid = threadIdx.x;
    const float4 v = *(const float4*)&x[(size_t)row * DMODEL + tid * 4];
    float s  = v.x + v.y + v.z + v.w;
    float s2 = v.x * v.x + v.y * v.y + v.z * v.z + v.w * v.w;
#pragma unroll
    for (int off = 1; off < 64; off <<= 1) {
        s  += __shfl_xor(s, off);
        s2 += __shfl_xor(s2, off);
    }
    __shared__ float red[8];
    const int wid = tid >> 6;
    if ((tid & 63) == 0) { red[wid] = s; red[4 + wid] = s2; }
    __syncthreads();
    s  = red[0] + red[1] + red[2] + red[3];
    s2 = red[4] + red[5] + red[6] + red[7];
    const float mu   = s * (1.f / DMODEL);
    const float var  = s2 * (1.f / DMODEL) - mu * mu;
    const float rstd = rsqrtf(var + 1e-5f);
    const float4 wv = *(const float4*)&w[tid * 4];
    const float4 bv = *(const float4*)&b[tid * 4];
    union { bf16 o[4]; uint2 u; } pk;
    pk.o[0] = (bf16)((v.x - mu) * rstd * wv.x + bv.x);
    pk.o[1] = (bf16)((v.y - mu) * rstd * wv.y + bv.y);
    pk.o[2] = (bf16)((v.z - mu) * rstd * wv.z + bv.z);
    pk.o[3] = (bf16)((v.w - mu) * rstd * wv.w + bv.w);
    *(uint2*)&xn[(size_t)row * DMODEL + tid * 4] = pk.u;
}

// ------------------------------------------------------- weight fp32->bf16
__global__ __launch_bounds__(256) void cvt_weights_kernel(
    const float* __restrict__ s0, const float* __restrict__ s1,
    const float* __restrict__ s2, const float* __restrict__ s3,
    const float* __restrict__ s4, const float* __restrict__ s5,
    const float* __restrict__ s6, const float* __restrict__ s7,
    bf16* __restrict__ d0, bf16* __restrict__ d1, bf16* __restrict__ d2,
    bf16* __restrict__ d3, bf16* __restrict__ d4, bf16* __restrict__ d5,
    bf16* __restrict__ d6, bf16* __restrict__ d7)
{
    const size_t gid = ((size_t)blockIdx.x * 256 + threadIdx.x) * 4;
    const float* s; bf16* dst; size_t off;
    if      (gid < 1048576) { s = s0; dst = d0; off = gid; }
    else if (gid < 2097152) { s = s1; dst = d1; off = gid - 1048576; }
    else if (gid < 2162688) { s = s2; dst = d2; off = gid - 2097152; }
    else if (gid < 2228224) { s = s3; dst = d3; off = gid - 2162688; }
    else if (gid < 2752512) { s = s4; dst = d4; off = gid - 2228224; }
    else if (gid < 3276800) { s = s5; dst = d5; off = gid - 2752512; }
    else if (gid < 3309568) { s = s6; dst = d6; off = gid - 3276800; }
    else if (gid < 3342336) { s = s7; dst = d7; off = gid - 3309568; }
    else return;
    const float4 v = *(const float4*)&s[off];
    union { bf16 o[4]; uint2 u; } pk;
    pk.o[0] = (bf16)v.x; pk.o[1] = (bf16)v.y; pk.o[2] = (bf16)v.z; pk.o[3] = (bf16)v.w;
    *(uint2*)&dst[off] = pk.u;
}

// ----------------------------------------------------------------- GEMM
// C[m,n] = sum_k A[m,k] * W[n,k]. m97 structure: global_load_lds(16B) into
// LINEAR LDS [rows][32], 2 barriers per K-step.
// EPI 0: bf16 store   1: f32+bf16 dual   2: softplus(v+bias[col]) -> bf16
// EPI 3: v + residual f32
template<int BM, int BN, int WTM, int WTN, int EPI>
__global__ __launch_bounds__(256) void gemm_k(
    const bf16* __restrict__ A0, long aDirStride, int lda,
    const bf16* __restrict__ W0, const bf16* __restrict__ W1, int ldw,
    void* __restrict__ C0, long cDirStride, int ldc,
    void* __restrict__ C1, long c1DirStride,
    const float* __restrict__ X0, const float* __restrict__ X1,
    int K)
{
    constexpr int WGN = BN / (WTN * 16);
    static_assert((BM * 32) % 2048 == 0 && (BN * 32) % 2048 == 0, "tile");
    __shared__ alignas(16) bf16 As[BM * 32];
    __shared__ alignas(16) bf16 Bs[BN * 32];
    const int tid = threadIdx.x;
    const int wid = tid >> 6, lane = tid & 63;
    const int wr = wid / WGN, wc = wid % WGN;
    const int bx = blockIdx.x, by = blockIdx.y, bz = blockIdx.z;
    const bf16* A = A0 + (long)bz * aDirStride + (long)by * BM * lda;
    const bf16* W = (bz ? W1 : W0) + (long)bx * BN * ldw;
    f32x4 acc[WTM][WTN] = {};
    for (int k0 = 0; k0 < K; k0 += 32) {
        constexpr int AP = BM * 32 / 2048;
#pragma unroll
        for (int p = 0; p < AP; ++p) {
            const int idx = (p * 256 + tid) * 8;
            const int r = idx >> 5, c = idx & 31;
            glds16(&A[(long)r * lda + k0 + c], &As[p * 2048 + wid * 512]);
        }
        constexpr int BP = BN * 32 / 2048;
#pragma unroll
        for (int p = 0; p < BP; ++p) {
            const int idx = (p * 256 + tid) * 8;
            const int r = idx >> 5, c = idx & 31;
            glds16(&W[(long)r * ldw + k0 + c], &Bs[p * 2048 + wid * 512]);
        }
        __syncthreads();
        const int rA = lane & 15, kO = (lane >> 4) * 8;
        bf16x8 af[WTM], bw[WTN];
#pragma unroll
        for (int i = 0; i < WTM; ++i)
            af[i] = *(const bf16x8*)&As[(wr * WTM * 16 + i * 16 + rA) * 32 + kO];
#pragma unroll
        for (int j = 0; j < WTN; ++j)
            bw[j] = *(const bf16x8*)&Bs[(wc * WTN * 16 + j * 16 + rA) * 32 + kO];
#pragma unroll
        for (int i = 0; i < WTM; ++i)
#pragma unroll
            for (int j = 0; j < WTN; ++j)
                acc[i][j] = __builtin_amdgcn_mfma_f32_16x16x32_bf16(af[i], bw[j], acc[i][j], 0, 0, 0);
        __syncthreads();
    }
    const int rl = (lane >> 4) * 4, cl = lane & 15;
    const int rowBase = by * BM + wr * WTM * 16;
    const int colBase = bx * BN + wc * WTN * 16;
#pragma unroll
    for (int i = 0; i < WTM; ++i)
#pragma unroll
        for (int j = 0; j < WTN; ++j) {
#pragma unroll
            for (int r = 0; r < 4; ++r) {
                const int row = rowBase + i * 16 + rl + r;
                const int col = colBase + j * 16 + cl;
                const float v = acc[i][j][r];
                if constexpr (EPI == 0) {
                    ((bf16*)C0 + (long)bz * cDirStride)[(long)row * ldc + col] = (bf16)v;
                } else if constexpr (EPI == 1) {
                    ((float*)C0 + (long)bz * cDirStride)[(long)row * ldc + col] = v;
                    ((bf16*)C1 + (long)bz * c1DirStride)[(long)row * ldc + col] = (bf16)v;
                } else if constexpr (EPI == 2) {
                    const float* bias = bz ? X1 : X0;
                    ((bf16*)C0 + (long)bz * cDirStride)[(long)row * ldc + col] =
                        (bf16)softplusf_(v + bias[col]);
                } else {
                    const long idx = (long)row * ldc + col;
                    ((float*)C0 + (long)bz * cDirStride)[idx] = v + (X0 + (long)bz * cDirStride)[idx];
                }
            }
        }
}

// --------------------------------------------------- depthwise conv4 + SiLU
#define CT 8
__global__ __launch_bounds__(256) void conv_silu_kernel(
    const bf16* __restrict__ xz, bf16* __restrict__ xc,
    const float* __restrict__ cwF, const float* __restrict__ cbF,
    const float* __restrict__ cwB, const float* __restrict__ cbB)
{
    const size_t gid = (size_t)blockIdx.x * 256 + threadIdx.x; // 2^18
    const int g = (int)(gid & 127);            // channel group (8 ch)
    const int tt = (int)((gid >> 7) & (LSEQ / CT - 1));
    const int b = (int)((gid >> 16) & 1);
    const int dir = (int)(gid >> 17);          // wave-uniform
    const int d0 = g * 8;
    const float* cw = dir ? cwB : cwF;
    const float* cb = dir ? cbB : cbF;
    float bias[8];
#pragma unroll
    for (int e = 0; e < 8; e += 4) *(float4*)&bias[e] = *(const float4*)&cb[d0 + e];
    float4 wv[8];
#pragma unroll
    for (int e = 0; e < 8; ++e) wv[e] = *(const float4*)&cw[(d0 + e) * 4];
    const int t0 = tt * CT;
    const size_t rowBase = (size_t)dir * MROWS * 2048 + (size_t)b * LSEQ * 2048;
    const bf16* src = xz + rowBase + d0;
    bf16* dst = xc + (size_t)dir * MROWS * DINNER + (size_t)b * LSEQ * DINNER
                + (size_t)t0 * DINNER + d0;

    float w0[8] = {}, w1[8] = {}, w2[8] = {};
    auto loadRow = [&](int ts, float* r) {
        if (ts >= 0 && ts < LSEQ) {
            const bf16x8 v = *(const bf16x8*)&src[(size_t)ts * 2048];
#pragma unroll
            for (int e = 0; e < 8; ++e) r[e] = (float)v[e];
        } else {
#pragma unroll
            for (int e = 0; e < 8; ++e) r[e] = 0.f;
        }
    };
    if (!dir) { loadRow(t0 - 3, w0); loadRow(t0 - 2, w1); loadRow(t0 - 1, w2); }
    else      { loadRow(t0,     w0); loadRow(t0 + 1, w1); loadRow(t0 + 2, w2); }

#pragma unroll
    for (int i = 0; i < CT; ++i) {
        float w3[8];
        loadRow(dir ? (t0 + i + 3) : (t0 + i), w3);
        bf16x8 o;
        if (!dir) {
#pragma unroll
            for (int e = 0; e < 8; ++e) {
                float acc = bias[e];
                acc = fmaf(wv[e].x, w0[e], acc);
                acc = fmaf(wv[e].y, w1[e], acc);
                acc = fmaf(wv[e].z, w2[e], acc);
                acc = fmaf(wv[e].w, w3[e], acc);
                const float s = acc * sigmoidf_(acc);
                o[e] = (bf16)s;
            }
        } else {
#pragma unroll
            for (int e = 0; e < 8; ++e) {
                float acc = bias[e];
                acc = fmaf(wv[e].w, w0[e], acc);
                acc = fmaf(wv[e].z, w1[e], acc);
                acc = fmaf(wv[e].y, w2[e], acc);
                acc = fmaf(wv[e].x, w3[e], acc);
                const float s = acc * sigmoidf_(acc);
                o[e] = (bf16)s;
            }
        }
        *(bf16x8*)&dst[(size_t)i * DINNER] = o;
#pragma unroll
        for (int e = 0; e < 8; ++e) { w0[e] = w1[e]; w1[e] = w2[e]; w2[e] = w3[e]; }
    }
}

// ------------------------------------------------- chunked selective scan
// lane = one channel d; 16 states in registers as 8 x float2 (v_pk_* ops).
// Fast path exploits a[n] == -(n+1): dA[n] = q^(n+1), q = exp(-dt).
// B/C rows via wave-uniform address expressions. hend/hin stored bf16.
__global__ __launch_bounds__(256) void scan_part1(
    const bf16* __restrict__ dt, const bf16* __restrict__ xc,
    const float* __restrict__ xdbl,
    bf16* __restrict__ hend, float* __restrict__ sdtOut,
    const float* __restrict__ AlogF, const float* __restrict__ AlogB)
{
    const int d = blockIdx.x * 256 + threadIdx.x;
    const int chunk = blockIdx.y;
    const int sb = blockIdx.z;
    const int dir = sb >> 1, b = sb & 1;
    const float* Alog = dir ? AlogB : AlogF;
    float a[16];
#pragma unroll
    for (int n = 0; n < 16; n += 4)
        *(float4*)&a[n] = *(const float4*)&Alog[d * 16 + n];
#pragma unroll
    for (int n = 0; n < 16; ++n) a[n] = -__expf(a[n]);
    bool fast = true;
#pragma unroll
    for (int n = 0; n < 16; ++n) fast = fast && (fabsf(a[n] + (float)(n + 1)) <= 1e-3f * (n + 1));
    const size_t base1 = (size_t)dir * MROWS * DINNER + (size_t)b * LSEQ * DINNER;
    const size_t base64 = (size_t)dir * MROWS * 64 + (size_t)b * LSEQ * 64;
    const int t0 = dir ? (LSEQ - 1) : 0;
    const int stp = dir ? -1 : 1;
    const int ts = t0 + stp * (chunk * SCT);
    const bf16* pdt = dt + base1 + (size_t)ts * DINNER + d;
    const bf16* pxc = xc + base1 + (size_t)ts * DINNER + d;
    const float* xb = xdbl + base64 + 32;      // uniform base for B rows
    const long s1 = (long)stp * DINNER;
    float sacc = 0.f;
    f32x2 h2[8];
#pragma unroll
    for (int j = 0; j < 8; ++j) h2[j] = (f32x2){0.f, 0.f};
    if (fast) {
#pragma unroll 4
        for (int i = 0; i < SCT; ++i) {
            const float dtv = (float)*pdt;
            const float u = (float)*pxc;
            const float dtu = dtv * u;
            sacc += dtv;
            const float* bRow = xb + (size_t)(ts + stp * i) * 64;   // uniform
            const float q = __expf(-dtv);
            const float q2 = q * q;
            const f32x2 qq = {q2, q2};
            f32x2 p = {q, q2};
#pragma unroll
            for (int j = 0; j < 8; ++j) {
                const f32x2 B2 = *(const f32x2*)&bRow[2 * j];
                h2[j] = __builtin_elementwise_fma(h2[j], p, B2 * dtu);
                p = p * qq;
            }
            pdt += s1; pxc += s1;
        }
    } else {
#pragma unroll 4
        for (int i = 0; i < SCT; ++i) {
            const float dtv = (float)*pdt;
            const float u = (float)*pxc;
            const float dtu = dtv * u;
            sacc += dtv;
            const float* bRow = xb + (size_t)(ts + stp * i) * 64;
#pragma unroll
            for (int j = 0; j < 8; ++j) {
                const f32x2 B2 = *(const f32x2*)&bRow[2 * j];
                const f32x2 dA = {__expf(dtv * a[2 * j]), __expf(dtv * a[2 * j + 1])};
                h2[j] = __builtin_elementwise_fma(h2[j], dA, B2 * dtu);
            }
            pdt += s1; pxc += s1;
        }
    }
    const size_t o = ((size_t)sb * SCH + chunk) * 16384 + (size_t)d * 16;
    bf16x8 p0, p1;
#pragma unroll
    for (int j = 0; j < 4; ++j) {
        p0[2 * j]     = (bf16)h2[j][0];     p0[2 * j + 1] = (bf16)h2[j][1];
        p1[2 * j]     = (bf16)h2[j + 4][0]; p1[2 * j + 1] = (bf16)h2[j + 4][1];
    }
    *(bf16x8*)&hend[o] = p0;
    *(bf16x8*)&hend[o + 8] = p1;
    sdtOut[((size_t)sb * SCH + chunk) * 1024 + d] = sacc;
}

// combine chunk summaries across chunks; hend[c] becomes h_in for chunk c.
__global__ __launch_bounds__(256) void scan_part2(
    bf16* __restrict__ hend, const float* __restrict__ sdt,
    const float* __restrict__ AlogF, const float* __restrict__ AlogB)
{
    const size_t gid = (size_t)blockIdx.x * 256 + threadIdx.x;  // 65536
    const int sb = (int)(gid >> 14);
    const int dn = (int)(gid & 16383);
    const int d = dn >> 4;
    const float* Alog = (sb >> 1) ? AlogB : AlogF;
    const float a_n = -__expf(Alog[dn]);
    float h = 0.f;
    size_t idx = (size_t)sb * SCH * 16384 + dn;
    size_t sidx = (size_t)sb * SCH * 1024 + d;
#pragma unroll 4
    for (int c = 0; c < SCH; ++c) {
        const float sd = sdt[sidx];
        const float pe = __expf(a_n * sd);
        const float he = (float)hend[idx];
        hend[idx] = (bf16)h;
        h = fmaf(pe, h, he);
        idx += 16384; sidx += 1024;
    }
}

// final pass: chunk scan from h_in; y = sum_n h*C; gate with silu(z)
__global__ __launch_bounds__(256) void scan_part3(
    const bf16* __restrict__ dt, const bf16* __restrict__ xc,
    const float* __restrict__ xdbl, const bf16* __restrict__ xz,
    const bf16* __restrict__ hin, bf16* __restrict__ yg,
    const float* __restrict__ AlogF, const float* __restrict__ AlogB,
    const float* __restrict__ DF, const float* __restrict__ DB)
{
    const int d = blockIdx.x * 256 + threadIdx.x;
    const int chunk = blockIdx.y;
    const int sb = blockIdx.z;
    const int dir = sb >> 1, b = sb & 1;
    const float* Alog = dir ? AlogB : AlogF;
    const float* Dw = dir ? DB : DF;
    float a[16];
#pragma unroll
    for (int n = 0; n < 16; n += 4)
        *(float4*)&a[n] = *(const float4*)&Alog[d * 16 + n];
#pragma unroll
    for (int n = 0; n < 16; ++n) a[n] = -__expf(a[n]);
    bool fast = true;
#pragma unroll
    for (int n = 0; n < 16; ++n) fast = fast && (fabsf(a[n] + (float)(n + 1)) <= 1e-3f * (n + 1));
    const float Dv = Dw[d];
    const size_t base1 = (size_t)dir * MROWS * DINNER + (size_t)b * LSEQ * DINNER;
    const size_t base64 = (size_t)dir * MROWS * 64 + (size_t)b * LSEQ * 64;
    const size_t baseZ = (size_t)dir * MROWS * 2048 + (size_t)b * LSEQ * 2048;
    const int t0 = dir ? (LSEQ - 1) : 0;
    const int stp = dir ? -1 : 1;
    const int ts = t0 + stp * (chunk * SCT);
    const bf16* pdt = dt + base1 + (size_t)ts * DINNER + d;
    const bf16* pxc = xc + base1 + (size_t)ts * DINNER + d;
    const float* xb = xdbl + base64 + 32;      // uniform base: B at +0, C at +16
    const bf16* pz = xz + baseZ + (size_t)ts * 2048 + 1024 + d;
    bf16* pyg = yg + base1 + (size_t)ts * DINNER + d;
    const long s1 = (long)stp * DINNER, sZ = (long)stp * 2048;
    f32x2 h2[8];
    const size_t o = ((size_t)sb * SCH + chunk) * 16384 + (size_t)d * 16;
    {
        const bf16x8 p0 = *(const bf16x8*)&hin[o];
        const bf16x8 p1 = *(const bf16x8*)&hin[o + 8];
#pragma unroll
        for (int j = 0; j < 4; ++j) {
            h2[j]     = (f32x2){(float)p0[2 * j], (float)p0[2 * j + 1]};
            h2[j + 4] = (f32x2){(float)p1[2 * j], (float)p1[2 * j + 1]};
        }
    }
    if (fast) {
#pragma unroll 4
        for (int i = 0; i < SCT; ++i) {
            const float dtv = (float)*pdt;
            const float u = (float)*pxc;
            const float dtu = dtv * u;
            const float* bRow = xb + (size_t)(ts + stp * i) * 64;   // uniform
            const float q = __expf(-dtv);
            const float q2 = q * q;
            const f32x2 qq = {q2, q2};
            f32x2 p = {q, q2};
            f32x2 y2 = {0.f, 0.f};
#pragma unroll
            for (int j = 0; j < 8; ++j) {
                const f32x2 B2 = *(const f32x2*)&bRow[2 * j];
                const f32x2 C2 = *(const f32x2*)&bRow[16 + 2 * j];
                h2[j] = __builtin_elementwise_fma(h2[j], p, B2 * dtu);
                y2 = __builtin_elementwise_fma(h2[j], C2, y2);
                p = p * qq;
            }
            const float y = y2[0] + y2[1];
            const float z = (float)*pz;
            const float out = (y + Dv * u) * (z * sigmoidf_(z));
            *pyg = (bf16)out;
            pdt += s1; pxc += s1; pz += sZ; pyg += s1;
        }
    } else {
#pragma unroll 4
        for (int i = 0; i < SCT; ++i) {
            const float dtv = (float)*pdt;
            const float u = (float)*pxc;
            const float dtu = dtv * u;
            const float* bRow = xb + (size_t)(ts + stp * i) * 64;
            f32x2 y2 = {0.f, 0.f};
#pragma unroll
            for (int j = 0; j < 8; ++j) {
                const f32x2 B2 = *(const f32x2*)&bRow[2 * j];
                const f32x2 C2 = *(const f32x2*)&bRow[16 + 2 * j];
                const f32x2 dA = {__expf(dtv * a[2 * j]), __expf(dtv * a[2 * j + 1])};
                h2[j] = __builtin_elementwise_fma(h2[j], dA, B2 * dtu);
                y2 = __builtin_elementwise_fma(h2[j], C2, y2);
            }
            const float y = y2[0] + y2[1];
            const float z = (float)*pz;
            const float out = (y + Dv * u) * (z * sigmoidf_(z));
            *pyg = (bf16)out;
            pdt += s1; pxc += s1; pz += sZ; pyg += s1;
        }
    }
}

// ------------------------------------------------------------------- launch
extern "C" void kernel_launch(void* const* d_in, const int* in_sizes, int n_in,
                              void* d_out, int out_size, void* d_ws, size_t ws_size,
                              hipStream_t stream)
{
    const float* x      = (const float*)d_in[0];
    const float* norm_w = (const float*)d_in[1];
    const float* norm_b = (const float*)d_in[2];
    const float* ipF  = (const float*)d_in[3];
    const float* cwF  = (const float*)d_in[4];
    const float* cbF  = (const float*)d_in[5];
    const float* xpF  = (const float*)d_in[6];
    const float* dtwF = (const float*)d_in[7];
    const float* dtbF = (const float*)d_in[8];
    const float* AlF  = (const float*)d_in[9];
    const float* DF   = (const float*)d_in[10];
    const float* opF  = (const float*)d_in[11];
    const float* ipB  = (const float*)d_in[12];
    const float* cwB  = (const float*)d_in[13];
    const float* cbB  = (const float*)d_in[14];
    const float* xpB  = (const float*)d_in[15];
    const float* dtwB = (const float*)d_in[16];
    const float* dtbB = (const float*)d_in[17];
    const float* AlB  = (const float*)d_in[18];
    const float* DB   = (const float*)d_in[19];
    const float* opB  = (const float*)d_in[20];

    char* ws = (char*)d_ws;
    size_t off = 0;
    auto alloc = [&](size_t bytes) -> void* {
        void* p = ws + off;
        off += (bytes + 255) & ~(size_t)255;
        return p;
    };
    bf16*  xn      = (bf16*)alloc((size_t)MROWS * DMODEL * 2);
    bf16*  win     = (bf16*)alloc((size_t)2 * 2048 * 512 * 2);
    bf16*  wxp     = (bf16*)alloc((size_t)2 * 64 * 1024 * 2);
    bf16*  wop     = (bf16*)alloc((size_t)2 * 512 * 1024 * 2);
    bf16*  wdt     = (bf16*)alloc((size_t)2 * 1024 * 32 * 2);
    bf16*  xz      = (bf16*)alloc((size_t)2 * MROWS * 2048 * 2);
    bf16*  xc      = (bf16*)alloc((size_t)2 * MROWS * 1024 * 2);
    float* xdbl    = (float*)alloc((size_t)2 * MROWS * 64 * 4);
    bf16*  xdbl_bf = (bf16*)alloc((size_t)2 * MROWS * 64 * 2);
    bf16*  dt      = (bf16*)alloc((size_t)2 * MROWS * 1024 * 2);
    bf16*  yg      = (bf16*)alloc((size_t)2 * MROWS * 1024 * 2);
    bf16*  hend    = (bf16*)alloc((size_t)4 * SCH * 16384 * 2);
    float* sdt     = (float*)alloc((size_t)4 * SCH * 1024 * 4);

    cvt_weights_kernel<<<3264, 256, 0, stream>>>(
        ipF, ipB, xpF, xpB, opF, opB, dtwF, dtwB,
        win, win + 2048 * 512, wxp, wxp + 64 * 1024,
        wop, wop + 512 * 1024, wdt, wdt + 1024 * 32);

    ln_kernel<<<MROWS, 256, 0, stream>>>(x, norm_w, norm_b, xn);

    // in_proj: [8192,512] x [2048,512]^T -> xz bf16 [dir][8192][2048]
    gemm_k<128, 128, 4, 4, 0><<<dim3(16, 64, 2), 256, 0, stream>>>(
        xn, 512, DMODEL, win, win + 2048 * 512, 512,
        xz, (long)MROWS * 2048, 2048, nullptr, 0, nullptr, nullptr, 512);

    conv_silu_kernel<<<1024, 256, 0, stream>>>(xz, xc, cwF, cbF, cwB, cbB);

    // x_proj: [8192,1024] x [64,1024]^T -> x_dbl f32 + bf16 shadow
    gemm_k<64, 64, 2, 2, 1><<<dim3(1, 128, 2), 256, 0, stream>>>(
        xc, (long)MROWS * 1024, 1024, wxp, wxp + 64 * 1024, 1024,
        xdbl, (long)MROWS * 64, 64, xdbl_bf, (long)MROWS * 64, nullptr, nullptr, 1024);

    // dt_proj: [8192,32] x [1024,32]^T -> softplus(+bias) bf16
    gemm_k<128, 128, 4, 4, 2><<<dim3(8, 64, 2), 256, 0, stream>>>(
        xdbl_bf, (long)MROWS * 64, 64, wdt, wdt + 1024 * 32, 32,
        dt, (long)MROWS * 1024, 1024, nullptr, 0, dtbF, dtbB, 32);

    // chunked scan: 128 chunks x 32 steps, lane = channel
    scan_part1<<<dim3(4, SCH, 4), 256, 0, stream>>>(dt, xc, xdbl, hend, sdt, AlF, AlB);
    scan_part2<<<256, 256, 0, stream>>>(hend, sdt, AlF, AlB);
    scan_part3<<<dim3(4, SCH, 4), 256, 0, stream>>>(dt, xc, xdbl, xz, hend, yg,
                                                    AlF, AlB, DF, DB);

    // out_proj + residual: [8192,1024] x [512,1024]^T -> d_out[row][dir*512+col]
    gemm_k<128, 128, 4, 4, 3><<<dim3(4, 64, 2), 256, 0, stream>>>(
        yg, (long)MROWS * 1024, 1024, wop, wop + 512 * 1024, 1024,
        d_out, 512, 1024, nullptr, 0, x, nullptr, 1024);
}